// Round 7
// baseline (198.309 us; speedup 1.0000x reference)
//
#include <hip/hip_runtime.h>

#define B_ 32
#define N_ 8732
#define N2_ 17464
#define N4_ 4366      // N2_/4 exactly
#define C_ 21
#define NCLS 20
#define K_ 200
#define CONF_T 0.01f
#define NMS_T 0.45f
#define TPB_S 256
#define TPB_N 512
#define POOL 1024
#define RANKCAP 512   // descend radix until candidate pool <= this (1-cand rank path)
#define HB 1024       // bins for radix levels 1-2; level 0 uses 8x64 per-wave

typedef unsigned long long u64;
typedef unsigned int u32;

// ---------------------------------------------------------------------------
// Kernel 1: per-anchor softmax DENOMINATOR only. Coalesced float4->LDS
// staging, per-row sequential max + exp-sum (same order as reference ->
// bit-identical m, inv), store float2{m, inv} to denom[B][2N] (4.47 MB,
// 10x less write traffic than materializing all 20 class planes).
// Grid: (ceil(N/256), B, 2 views).
// ---------------------------------------------------------------------------
__global__ __launch_bounds__(TPB_S) void denom_kernel(
    const float* __restrict__ conf1, const float* __restrict__ conf2,
    float2* __restrict__ denom)
{
  __shared__ float lds[TPB_S * C_];   // 21 KB
  const int t = threadIdx.x;
  const int tile = blockIdx.x * TPB_S;
  const int b = blockIdx.y;
  const int view = blockIdx.z;
  int cnt = N_ - tile; if (cnt > TPB_S) cnt = TPB_S;   // 256 or 28 (both %4==0)
  const float* conf = view ? conf2 : conf1;
  const float4* src = (const float4*)(conf + ((size_t)b * N_ + tile) * C_);  // 16B-aligned
  float4* l4 = (float4*)lds;
  const int n4 = (cnt * C_) >> 2;     // 1344 or 147 (exact)
  for (int i = t; i < n4; i += TPB_S) l4[i] = src[i];
  __syncthreads();
  if (t < cnt) {
    float x[C_];
#pragma unroll
    for (int i = 0; i < C_; ++i) x[i] = lds[t * C_ + i];  // stride-21: 2-way, free
    float m = x[0];
#pragma unroll
    for (int i = 1; i < C_; ++i) m = fmaxf(m, x[i]);      // same order as before
    float sum = 0.0f;
#pragma unroll
    for (int i = 0; i < C_; ++i) sum += __expf(x[i] - m); // same order as before
    float inv = 1.0f / sum;
    denom[(size_t)b * N2_ + (size_t)view * N_ + tile + t] = make_float2(m, inv);
  }
}

// ---------------------------------------------------------------------------
// Kernel 2: per-(image,class). Scores computed ON THE FLY from conf (strided
// dword gathers, L3-resident after kernel 1) + denom (float4-pair coalesced):
// score = __expf(conf - m) * inv  — expression-identical to the materialized
// pipeline -> bit-identical selection. Block remap bimg=blk&31 puts an
// image's 20 class-blocks on one XCD (dispatch round-robins mod 8) for
// conf/denom L2 locality. All later phases = round-3 hardware-verified code:
// per-wave 64-bin radix -> ballot-collect -> b128 rank-by-counting -> decode
// -> triangle IoU -> word-chunked static greedy scan -> in-wave compact.
// One 512-thread block per (b, c).
// ---------------------------------------------------------------------------
__global__ __launch_bounds__(TPB_N, 2) void nms_kernel(
    const float* __restrict__ conf1,
    const float* __restrict__ conf2,
    const float2* __restrict__ denom,
    const float4* __restrict__ loc1,
    const float4* __restrict__ loc2,
    const float4* __restrict__ dbox,
    float* __restrict__ out)
{
  const int t = threadIdx.x;
  const int lane = t & 63;
  const int wv = t >> 6;
  const int bimg = blockIdx.x & 31;          // XCD-affinity remap (32 % 8 == 0)
  const int cls = 1 + (blockIdx.x >> 5);
  float* ob = out + ((size_t)bimg * C_ + cls) * K_ * 5;

  __shared__ u32 hist[HB];               // 4 KB (L0: 8x64 per-wave; L1/L2: 1024)
  __shared__ u64 pool[POOL] __attribute__((aligned(16)));  // 8 KB, pre-zeroed
  __shared__ u64 spool[256];             // 2 KB, rank-ordered top-200
  __shared__ float4 bb[K_];              // 3.2 KB
  __shared__ float bar[K_];
  __shared__ u64 rowmask[K_][4];         // 6.4 KB (triangle: row j has cols>j)
  __shared__ u64 validmask[4];
  __shared__ u32 wtot[8];
  __shared__ u32 sh_sel, sh_Sb, sh_Sn, sh_nc;

  // ---- fused output zeroing (replaces hipMemsetAsync) ----
  {
    const float4 z4 = make_float4(0.f, 0.f, 0.f, 0.f);
    if (t < 250) ((float4*)ob)[t] = z4;                      // own (b,cls) slice
    if (cls == 1 && t >= 256 && t < 506)                     // background class 0
      ((float4*)(out + (size_t)bimg * C_ * K_ * 5))[t - 256] = z4;
  }

  // ---- compute this (b,c)'s 17464 scores into registers (one global pass) ----
  float4 v[9];
#pragma unroll
  for (int k = 0; k < 9; ++k) {
    int i = t + k * TPB_N;              // float4-group index (anchors 4i..4i+3)
    if (i < N4_) {
      const int a0 = i << 2;            // group never straddles view (8732%4==0)
      const float* cb = (a0 < N_)
        ? conf1 + ((size_t)bimg * N_ + a0) * C_ + cls
        : conf2 + ((size_t)bimg * N_ + (a0 - N_)) * C_ + cls;
      const float s0 = cb[0], s1 = cb[C_], s2 = cb[2 * C_], s3 = cb[3 * C_];
      const float2* dd = denom + (size_t)bimg * N2_ + a0;
      const float4 dA = *(const float4*)dd;        // {m0,inv0,m1,inv1} 16B-aligned
      const float4 dB = *(const float4*)(dd + 2);  // {m2,inv2,m3,inv3}
      v[k].x = __expf(s0 - dA.x) * dA.y;
      v[k].y = __expf(s1 - dA.z) * dA.w;
      v[k].z = __expf(s2 - dB.x) * dB.y;
      v[k].w = __expf(s3 - dB.z) * dB.w;
    } else {
      v[k] = make_float4(0.f, 0.f, 0.f, 0.f);
    }
  }

  // ---- zero L0 hist (8x64) + whole pool (enables unconditional b128 rank) ----
  hist[t] = 0u;
  pool[t] = 0ULL; pool[t + TPB_N] = 0ULL;
  if (t == 0) sh_nc = 0u;
  __syncthreads();

  // ---- level 0: per-wave 64-bin histograms, bin = (key>>20)-960 in [2,56] ----
  {
    const int hb = wv << 6;
#pragma unroll
    for (int k = 0; k < 9; ++k) {
      float ss[4] = {v[k].x, v[k].y, v[k].z, v[k].w};
#pragma unroll
      for (int c2 = 0; c2 < 4; ++c2) {
        float s = ss[c2];
        if (s > CONF_T)
          atomicAdd(&hist[hb + ((__float_as_uint(s) >> 20) - 960u)], 1u);
      }
    }
  }
  __syncthreads();

  // ---- single-wave merge + suffix scan + bin select (wave 0 only) ----
  if (t < 64) {
    u32 c = hist[t]       + hist[t + 64]  + hist[t + 128] + hist[t + 192]
          + hist[t + 256] + hist[t + 320] + hist[t + 384] + hist[t + 448];
    u32 x = c;
#pragma unroll
    for (int off = 1; off < 64; off <<= 1) {
      u32 y = __shfl_down(x, off);
      if (lane + off < 64) x += y;
    }                                   // x = sum_{h>=t} hist[h]
    u32 total = __shfl(x, 0);
    u32 Sn = x - c;                     // suffix strictly above my bin
    if (total < (u32)K_) {
      if (t == 0) sh_sel = 0xFFFFFFFFu; // undershoot: take all valid (<200)
    } else if (x >= (u32)K_ && Sn < (u32)K_) {
      sh_sel = (u32)t; sh_Sb = x; sh_Sn = Sn;   // unique lane
    }
  }
  __syncthreads();

  u32 loKey, prefix = 0, Gacc = 0;
  bool needMore = false;
  if (sh_sel == 0xFFFFFFFFu) {
    loKey = 1u;                         // all s > CONF_T pass (their keys >= 1)
  } else {
    prefix = sh_sel + 960u;             // real key>>20 value
    loKey = prefix << 20;
    Gacc = sh_Sn;
    needMore = sh_Sb > (u32)RANKCAP;
  }

  // ---- levels 1-2: refine within selected bin (1024 bins, single shared) ----
  for (int lvl = 1; lvl <= 2 && needMore; ++lvl) {
    const int shift = (lvl == 1) ? 10 : 0;
    const int mshift = shift + 10;
    for (int h = t; h < HB; h += TPB_N) hist[h] = 0u;
    __syncthreads();
#pragma unroll
    for (int k = 0; k < 9; ++k) {
      float ss[4] = {v[k].x, v[k].y, v[k].z, v[k].w};
#pragma unroll
      for (int c2 = 0; c2 < 4; ++c2) {
        float s = ss[c2];
        if (s > CONF_T) {
          u32 key = __float_as_uint(s);
          if ((key >> mshift) == prefix)
            atomicAdd(&hist[(key >> shift) & (HB - 1)], 1u);
        }
      }
    }
    __syncthreads();
    // suffix sums over 1024 bins: 2 bins/thread + wave scan
    u32 c0 = hist[2 * t], c1 = hist[2 * t + 1];
    u32 T = c0 + c1;
    u32 x = T;
#pragma unroll
    for (int off = 1; off < 64; off <<= 1) {
      u32 y = __shfl_down(x, off);
      if (lane + off < 64) x += y;
    }
    if (lane == 0) wtot[wv] = x;
    __syncthreads();
    u32 wafter = 0;
    for (int w = wv + 1; w < 8; ++w) wafter += wtot[w];
    u32 after_me = (x - T) + wafter;
    u32 S1 = c1 + after_me, S0 = c0 + S1;
    hist[2 * t] = S0; hist[2 * t + 1] = S1;
    __syncthreads();
    u32 need = (u32)K_ - Gacc;
    for (int h = t; h < HB; h += TPB_N) {
      u32 Sb = hist[h];
      u32 Sn2 = (h + 1 < HB) ? hist[h + 1] : 0u;
      if (Sb >= need && Sn2 < need) { sh_sel = (u32)h; sh_Sb = Sb; sh_Sn = Sn2; }
    }
    __syncthreads();
    prefix = (prefix << 10) | sh_sel;
    u32 candTotal = Gacc + sh_Sb;
    Gacc += sh_Sn;
    loKey = prefix << shift;
    needMore = (candTotal > (u32)RANKCAP) && (lvl < 2);
  }

  // ---- ballot-collect candidates (key >= loKey) into pool, 1 atomic/wave ----
#pragma unroll
  for (int k = 0; k < 9; ++k) {
    int i = t + k * TPB_N;
    float ss[4] = {v[k].x, v[k].y, v[k].z, v[k].w};
#pragma unroll
    for (int c2 = 0; c2 < 4; ++c2) {
      float s = ss[c2];
      u32 key = __float_as_uint(s);
      bool pred = (s > CONF_T) && (key >= loKey);
      u64 bal = __ballot(pred);
      if (bal) {
        u32 wb = 0;
        if (lane == 0) wb = atomicAdd(&sh_nc, (u32)__popcll(bal));
        wb = __shfl(wb, 0);
        if (pred) {
          u32 pos = wb + (u32)__popcll(bal & ((1ULL << lane) - 1ULL));
          if (pos < (u32)POOL)
            pool[pos] = ((u64)key << 32) | (u64)(0xFFFFFFFFu - (u32)(i * 4 + c2));
        }
      }
    }
  }
  __syncthreads();

  // ---- rank-by-counting: composite keys unique -> rank = #{keys > mine} ----
  // pool pre-zeroed, so b128 reads past nc compare against 0 (harmless).
  u32 nc = sh_nc < (u32)POOL ? sh_nc : (u32)POOL;
  if (t < 256) spool[t] = 0ULL;
  const bool dual = nc > (u32)TPB_N;    // block-uniform; rare (lvl-2 exit >512)
  u64 my0 = (t < (int)nc) ? pool[t] : 0ULL;
  u64 my1 = (dual && t + TPB_N < (int)nc) ? pool[t + TPB_N] : 0ULL;
  __syncthreads();
  u32 r0 = 0, r1 = 0;
  if ((u32)(t & ~63) < nc) {            // whole waves past nc skip the loop
    if (!dual) {
#pragma unroll 4
      for (u32 k = 0; k < nc; k += 2) { // 2 keys per ds_read_b128
        ulonglong2 pk = *(const ulonglong2*)&pool[k];
        r0 += (pk.x > my0) ? 1u : 0u;
        r0 += (pk.y > my0) ? 1u : 0u;
      }
    } else {
#pragma unroll 4
      for (u32 k = 0; k < nc; k += 2) {
        ulonglong2 pk = *(const ulonglong2*)&pool[k];
        r0 += (pk.x > my0) ? 1u : 0u;
        r0 += (pk.y > my0) ? 1u : 0u;
        r1 += (pk.x > my1) ? 1u : 0u;
        r1 += (pk.y > my1) ? 1u : 0u;
      }
    }
  }
  if (my0 != 0ULL && r0 < (u32)K_) spool[r0] = my0;
  if (dual && my1 != 0ULL && r1 < (u32)K_) spool[r1] = my1;
  __syncthreads();
  // spool[0..199] == exact top_k (desc score, ties by ascending index)

  // ---- decode boxes for top-200; idle threads 256+ zero rowmask ----
  float scv = 0.f;
  if (t < K_) {
    float x1 = 0.f, y1 = 0.f, x2 = 0.f, y2 = 0.f, area = 0.f;
    u64 e = spool[t];
    u32 kb = (u32)(e >> 32);
    if (kb != 0u) {
      scv = __uint_as_float(kb);
      u32 idx = 0xFFFFFFFFu - (u32)(e & 0xFFFFFFFFu);
      int nn = (idx < (u32)N_) ? (int)idx : (int)(idx - N_);
      float4 l = (idx < (u32)N_) ? loc1[(size_t)bimg * N_ + nn]
                                 : loc2[(size_t)bimg * N_ + nn];
      float4 d = dbox[nn];
      float cx = d.x + l.x * 0.1f * d.z;
      float cy = d.y + l.y * 0.1f * d.w;
      float w = d.z * __expf(l.z * 0.2f);
      float h = d.w * __expf(l.w * 0.2f);
      x1 = cx - w * 0.5f; y1 = cy - h * 0.5f;
      x2 = cx + w * 0.5f; y2 = cy + h * 0.5f;
      if (idx >= (u32)N_) {   // horizontal flip of second (TTA) view
        float tmp = 1.0f - x2; x2 = 1.0f - x1; x1 = tmp;
      }
      area = (x2 - x1) * (y2 - y1);
    }
    bb[t] = make_float4(x1, y1, x2, y2);
    bar[t] = area;
  } else if (t >= 256) {
    for (int i = t - 256; i < 4 * K_; i += 256) ((u64*)rowmask)[i] = 0ULL;
  }
  {
    bool myvalid = (t < K_) && (scv > CONF_T);
    u64 bal = __ballot(myvalid);
    if (lane == 0 && wv < 4) validmask[wv] = bal;
  }
  __syncthreads();

  // ---- triangle IoU: row j, cols j+1..199, split in half across 400 threads ----
  if (t < 2 * K_) {
    const int j = (t < K_) ? t : (t - K_);
    const int h = (t < K_) ? 0 : 1;
    const int L = K_ - 1 - j;             // #cols after j
    const int half = (L + 1) >> 1;
    const int s0c = j + 1 + (h ? half : 0);
    const int e0c = h ? K_ : (j + 1 + half);
    if (s0c < e0c) {
      float4 mb = bb[j];
      float ma = bar[j];
      for (int w = (s0c >> 6); w <= ((e0c - 1) >> 6); ++w) {
        int ka = (w << 6) > s0c ? (w << 6) : s0c;
        int kb2 = ((w + 1) << 6) < e0c ? ((w + 1) << 6) : e0c;
        u64 m = 0ULL;
        for (int k2 = ka; k2 < kb2; ++k2) {
          float4 obx = bb[k2];
          float ox1 = fmaxf(mb.x, obx.x);
          float oy1 = fmaxf(mb.y, obx.y);
          float ox2 = fminf(mb.z, obx.z);
          float oy2 = fminf(mb.w, obx.w);
          float inter = fmaxf(ox2 - ox1, 0.f) * fmaxf(oy2 - oy1, 0.f);
          float uni = ma + bar[k2] - inter;
          m |= (inter > NMS_T * uni) ? (1ULL << (k2 & 63)) : 0ULL;
        }
        if (m) atomicOr(&rowmask[j][w], m);
      }
    }
  }
  __syncthreads();
  // waves 1-7 are done; wave 0 finishes the block alone.

  // ---- static pipelined greedy scan, chunked by word (triangle: j>=64 never
  // touches word 0, etc.), then in-wave compact ----
  if (t < 64) {
    const u64 vv0 = validmask[0], vv1 = validmask[1];
    const u64 vv2 = validmask[2], vv3 = validmask[3];
    u64 s0 = 0, s1 = 0, s2 = 0, s3 = 0;
    u64 k0 = 0, k1 = 0, k2m = 0, k3 = 0;
#pragma unroll 8
    for (int j = 0; j < 64; ++j) {
      u64 q0 = rowmask[j][0], q1 = rowmask[j][1], q2 = rowmask[j][2], q3 = rowmask[j][3];
      u64 bit = 1ULL << j;
      if ((vv0 & bit) && !(s0 & bit)) { s0 |= q0; s1 |= q1; s2 |= q2; s3 |= q3; k0 |= bit; }
    }
#pragma unroll 8
    for (int j = 64; j < 128; ++j) {
      u64 q1 = rowmask[j][1], q2 = rowmask[j][2], q3 = rowmask[j][3];
      u64 bit = 1ULL << (j & 63);
      if ((vv1 & bit) && !(s1 & bit)) { s1 |= q1; s2 |= q2; s3 |= q3; k1 |= bit; }
    }
#pragma unroll 8
    for (int j = 128; j < 192; ++j) {
      u64 q2 = rowmask[j][2], q3 = rowmask[j][3];
      u64 bit = 1ULL << (j & 63);
      if ((vv2 & bit) && !(s2 & bit)) { s2 |= q2; s3 |= q3; k2m |= bit; }
    }
#pragma unroll
    for (int j = 192; j < K_; ++j) {
      u64 q3 = rowmask[j][3];
      u64 bit = 1ULL << (j & 63);
      if ((vv3 & bit) && !(s3 & bit)) { s3 |= q3; k3 |= bit; }
    }
    // ---- compact kept entries (lane-parallel within wave 0) ----
    const u32 n0 = (u32)__popcll(k0);
    const u32 n01 = n0 + (u32)__popcll(k1);
    const u32 n012 = n01 + (u32)__popcll(k2m);
    const u64 below = (1ULL << lane) - 1ULL;
#pragma unroll
    for (int w = 0; w < 4; ++w) {
      int j = (w << 6) + lane;
      if (j < K_) {
        u64 kw = (w == 0) ? k0 : (w == 1) ? k1 : (w == 2) ? k2m : k3;
        if ((kw >> lane) & 1ULL) {
          int pos2 = (int)__popcll(kw & below)
                  + (int)((w == 0) ? 0u : (w == 1) ? n0 : (w == 2) ? n01 : n012);
          u64 e = spool[j];
          float sc = __uint_as_float((u32)(e >> 32));
          float4 bx = bb[j];
          float* o = ob + (size_t)pos2 * 5;
          o[0] = sc; o[1] = bx.x; o[2] = bx.y; o[3] = bx.z; o[4] = bx.w;
        }
      }
    }
  }
}

extern "C" void kernel_launch(void* const* d_in, const int* in_sizes, int n_in,
                              void* d_out, int out_size, void* d_ws, size_t ws_size,
                              hipStream_t stream) {
  const float* loc1 = (const float*)d_in[0];
  const float* conf1 = (const float*)d_in[1];
  const float* loc2 = (const float*)d_in[2];
  const float* conf2 = (const float*)d_in[3];
  const float* dbox = (const float*)d_in[4];
  float* out = (float*)d_out;
  float2* denom = (float2*)d_ws;   // [B, 2N] float2{m, inv} = 4.47 MB

  dim3 g1((N_ + TPB_S - 1) / TPB_S, B_, 2);
  denom_kernel<<<g1, TPB_S, 0, stream>>>(conf1, conf2, denom);

  nms_kernel<<<B_ * NCLS, TPB_N, 0, stream>>>(
      conf1, conf2, denom, (const float4*)loc1, (const float4*)loc2,
      (const float4*)dbox, out);
}

// Round 8
// 151.569 us; speedup vs baseline: 1.3084x; 1.3084x over previous
//
#include <hip/hip_runtime.h>

#define B_ 32
#define N_ 8732
#define N2_ 17464
#define N4_ 4366      // N2_/4 exactly
#define C_ 21
#define NCLS 20
#define K_ 200
#define CONF_T 0.01f
#define NMS_T 0.45f
#define TPB_S 256
#define TPB_N 512
#define POOL 1024
#define RANKCAP 512   // descend radix until candidate pool <= this (1-cand rank path)
#define HB0 2048      // level-0 bins (shift 15)
#define HB 1024       // refine-level bins (shift 5 then 0)
#define BIN0 30791u   // 0x3C23D70B >> 15: bin offset for level 0

typedef unsigned long long u64;
typedef unsigned int u32;

// ---------------------------------------------------------------------------
// Kernel 1 (round-6 hardware-verified, unchanged): softmax over C=21.
// Coalesced float4->LDS staging, per-row compute in registers, DIRECT global
// dword stores per class plane (lane-consecutive n -> coalesced 256B/wave).
// Grid: (ceil(N/256), B, 2 views).
// ---------------------------------------------------------------------------
__global__ __launch_bounds__(TPB_S) void softmax_kernel(
    const float* __restrict__ conf1, const float* __restrict__ conf2,
    float* __restrict__ scores)
{
  __shared__ float lds[TPB_S * C_];   // 21 KB
  const int t = threadIdx.x;
  const int tile = blockIdx.x * TPB_S;
  const int b = blockIdx.y;
  const int view = blockIdx.z;
  int cnt = N_ - tile; if (cnt > TPB_S) cnt = TPB_S;   // 256 or 28 (both %4==0)
  const float* conf = view ? conf2 : conf1;
  const float4* src = (const float4*)(conf + ((size_t)b * N_ + tile) * C_);  // 16B-aligned
  float4* l4 = (float4*)lds;
  const int n4 = (cnt * C_) >> 2;
  for (int i = t; i < n4; i += TPB_S) l4[i] = src[i];
  __syncthreads();
  if (t < cnt) {
    float x[C_];
#pragma unroll
    for (int i = 0; i < C_; ++i) x[i] = lds[t * C_ + i];  // stride-21: 2-way, free
    float m = x[0];
#pragma unroll
    for (int i = 1; i < C_; ++i) m = fmaxf(m, x[i]);
    float e[C_];
    float sum = 0.0f;
#pragma unroll
    for (int i = 0; i < C_; ++i) { e[i] = __expf(x[i] - m); sum += e[i]; }
    float inv = 1.0f / sum;   // one IEEE div, not 20
    float* o = scores + ((size_t)b * NCLS) * N2_ + (size_t)view * N_ + (tile + t);
#pragma unroll
    for (int c = 1; c < C_; ++c) { *o = e[c] * inv; o += N2_; }
  }
}

// ---------------------------------------------------------------------------
// Kernel 2: per-(image,class). Round-6 verified structure with ONE change:
// level-0 radix moves from 64 exponent bins (shift 20; scores cluster in ~3
// bins -> ~30-60x LDS same-address atomic serialization, and the fat bin
// forced a level-1 refine pass nearly every block) to a single 2048-bin
// histogram at SHIFT 15: (key>>15)-30791 in [0,1721]. Mantissa-high bits
// spread the cluster over ~300 bins (atomics ~2-3x) and bin granularity
// makes Sb-Sn ~ tens -> refine levels (shift 5, then 0) almost never run.
// Selection semantics identical: any loKey with count in [200,1024] yields
// the same exact rank-by-counting top-200. One 512-thread block per (b, c).
// ---------------------------------------------------------------------------
__global__ __launch_bounds__(TPB_N, 2) void nms_kernel(
    const float* __restrict__ scores,
    const float4* __restrict__ loc1,
    const float4* __restrict__ loc2,
    const float4* __restrict__ dbox,
    float* __restrict__ out)
{
  const int t = threadIdx.x;
  const int lane = t & 63;
  const int wv = t >> 6;
  const int bimg = blockIdx.x / NCLS;
  const int cls = 1 + (blockIdx.x % NCLS);
  const float4* sc4 = (const float4*)(scores + ((size_t)bimg * NCLS + (cls - 1)) * N2_);
  float* ob = out + ((size_t)bimg * C_ + cls) * K_ * 5;

  __shared__ u32 hist[HB0];              // 8 KB (L0: 2048 @shift15; refine: first 1024)
  __shared__ u64 pool[POOL] __attribute__((aligned(16)));  // 8 KB, pre-zeroed
  __shared__ u64 spool[256];             // 2 KB, rank-ordered top-200
  __shared__ float4 bb[K_];              // 3.2 KB
  __shared__ float bar[K_];
  __shared__ u64 rowmask[K_][4];         // 6.4 KB (triangle: row j has cols>j)
  __shared__ u64 validmask[4];
  __shared__ u32 wtot[8];
  __shared__ u32 sh_sel, sh_Sb, sh_Sn, sh_nc;

  // ---- fused output zeroing (replaces hipMemsetAsync) ----
  {
    const float4 z4 = make_float4(0.f, 0.f, 0.f, 0.f);
    if (t < 250) ((float4*)ob)[t] = z4;                      // own (b,cls) slice
    if (cls == 1 && t >= 256 && t < 506)                     // background class 0
      ((float4*)(out + (size_t)bimg * C_ * K_ * 5))[t - 256] = z4;
  }

  // ---- load this (b,c)'s 17464 scores into registers: the ONLY global pass ----
  float4 v[9];
#pragma unroll
  for (int k = 0; k < 9; ++k) {
    int i = t + k * TPB_N;
    v[k] = (i < N4_) ? sc4[i] : make_float4(0.f, 0.f, 0.f, 0.f);
  }

  // ---- zero L0 hist (2048) + whole pool (enables unconditional b128 rank) ----
  hist[t] = 0u; hist[t + 512] = 0u; hist[t + 1024] = 0u; hist[t + 1536] = 0u;
  pool[t] = 0ULL; pool[t + TPB_N] = 0ULL;
  if (t == 0) sh_nc = 0u;
  __syncthreads();

  // ---- level 0: 2048-bin histogram at shift 15 ----
  // valid keys 0x3C23D70B..0x3F800000 -> (key>>15)-30791 in [0,1721]
#pragma unroll
  for (int k = 0; k < 9; ++k) {
    float ss[4] = {v[k].x, v[k].y, v[k].z, v[k].w};
#pragma unroll
    for (int c2 = 0; c2 < 4; ++c2) {
      float s = ss[c2];
      if (s > CONF_T)
        atomicAdd(&hist[(__float_as_uint(s) >> 15) - BIN0], 1u);
    }
  }
  __syncthreads();

  // ---- suffix sums over 2048 bins: 4 bins/thread + wave scan ----
  {
    u32 c0 = hist[4 * t + 0], c1 = hist[4 * t + 1];
    u32 c2b = hist[4 * t + 2], c3 = hist[4 * t + 3];
    u32 T = c0 + c1 + c2b + c3;
    u32 x = T;
#pragma unroll
    for (int off = 1; off < 64; off <<= 1) {
      u32 y = __shfl_down(x, off);
      if (lane + off < 64) x += y;
    }                                   // x = suffix-incl sum of thread totals in wave
    if (lane == 0) wtot[wv] = x;
    __syncthreads();
    u32 wafter = 0;
    for (int w = wv + 1; w < 8; ++w) wafter += wtot[w];
    u32 after_me = (x - T) + wafter;    // totals of threads strictly after t
    u32 S3 = c3 + after_me, S2 = c2b + S3, S1 = c1 + S2, S0 = c0 + S1;
    hist[4 * t + 0] = S0; hist[4 * t + 1] = S1;
    hist[4 * t + 2] = S2; hist[4 * t + 3] = S3;
  }
  __syncthreads();

  u32 loKey, prefix = 0, Gacc = 0;
  bool needMore = false;
  {
    u32 total = hist[0];                // block-uniform
    if (total < (u32)K_) {
      loKey = 1u;                       // undershoot: take all valid (<200)
    } else {
      for (int h = t; h < HB0; h += TPB_N) {
        u32 Sb = hist[h];
        u32 Sn = (h + 1 < HB0) ? hist[h + 1] : 0u;
        if (Sb >= (u32)K_ && Sn < (u32)K_) { sh_sel = (u32)h; sh_Sb = Sb; sh_Sn = Sn; }
      }
      __syncthreads();                  // uniform branch: total is block-uniform
      prefix = sh_sel + BIN0;           // real key>>15 value
      loKey = prefix << 15;
      Gacc = sh_Sn;
      needMore = sh_Sb > (u32)RANKCAP;  // rare: one 32768-key window holding >312
    }
  }

  // ---- refine levels (rare): shift 5 (1024 bins) then shift 0 (32 bins) ----
  for (int lvl = 1; lvl <= 2 && needMore; ++lvl) {
    const int shift = (lvl == 1) ? 5 : 0;
    const int mshift = (lvl == 1) ? 15 : 5;
    const u32 bmask = (lvl == 1) ? 1023u : 31u;
    for (int h = t; h < HB; h += TPB_N) hist[h] = 0u;
    __syncthreads();
#pragma unroll
    for (int k = 0; k < 9; ++k) {
      float ss[4] = {v[k].x, v[k].y, v[k].z, v[k].w};
#pragma unroll
      for (int c2 = 0; c2 < 4; ++c2) {
        float s = ss[c2];
        if (s > CONF_T) {
          u32 key = __float_as_uint(s);
          if ((key >> mshift) == prefix)
            atomicAdd(&hist[(key >> shift) & bmask], 1u);
        }
      }
    }
    __syncthreads();
    // suffix sums over 1024 bins: 2 bins/thread + wave scan
    u32 c0 = hist[2 * t], c1 = hist[2 * t + 1];
    u32 T = c0 + c1;
    u32 x = T;
#pragma unroll
    for (int off = 1; off < 64; off <<= 1) {
      u32 y = __shfl_down(x, off);
      if (lane + off < 64) x += y;
    }
    if (lane == 0) wtot[wv] = x;
    __syncthreads();
    u32 wafter = 0;
    for (int w = wv + 1; w < 8; ++w) wafter += wtot[w];
    u32 after_me = (x - T) + wafter;
    u32 S1 = c1 + after_me, S0 = c0 + S1;
    hist[2 * t] = S0; hist[2 * t + 1] = S1;
    __syncthreads();
    u32 need = (u32)K_ - Gacc;
    for (int h = t; h < HB; h += TPB_N) {
      u32 Sb = hist[h];
      u32 Sn2 = (h + 1 < HB) ? hist[h + 1] : 0u;
      if (Sb >= need && Sn2 < need) { sh_sel = (u32)h; sh_Sb = Sb; sh_Sn = Sn2; }
    }
    __syncthreads();
    prefix = (prefix << ((lvl == 1) ? 10 : 5)) | sh_sel;
    u32 candTotal = Gacc + sh_Sb;
    Gacc += sh_Sn;
    loKey = prefix << shift;
    needMore = (candTotal > (u32)RANKCAP) && (lvl < 2);
  }

  // ---- ballot-collect candidates (key >= loKey) into pool, 1 atomic/wave ----
#pragma unroll
  for (int k = 0; k < 9; ++k) {
    int i = t + k * TPB_N;
    float ss[4] = {v[k].x, v[k].y, v[k].z, v[k].w};
#pragma unroll
    for (int c2 = 0; c2 < 4; ++c2) {
      float s = ss[c2];
      u32 key = __float_as_uint(s);
      bool pred = (s > CONF_T) && (key >= loKey);
      u64 bal = __ballot(pred);
      if (bal) {
        u32 wb = 0;
        if (lane == 0) wb = atomicAdd(&sh_nc, (u32)__popcll(bal));
        wb = __shfl(wb, 0);
        if (pred) {
          u32 pos = wb + (u32)__popcll(bal & ((1ULL << lane) - 1ULL));
          if (pos < (u32)POOL)
            pool[pos] = ((u64)key << 32) | (u64)(0xFFFFFFFFu - (u32)(i * 4 + c2));
        }
      }
    }
  }
  __syncthreads();

  // ---- rank-by-counting: composite keys unique -> rank = #{keys > mine} ----
  // pool pre-zeroed, so b128 reads past nc compare against 0 (harmless).
  u32 nc = sh_nc < (u32)POOL ? sh_nc : (u32)POOL;
  if (t < 256) spool[t] = 0ULL;
  const bool dual = nc > (u32)TPB_N;    // block-uniform; rare (lvl-2 exit >512)
  u64 my0 = (t < (int)nc) ? pool[t] : 0ULL;
  u64 my1 = (dual && t + TPB_N < (int)nc) ? pool[t + TPB_N] : 0ULL;
  __syncthreads();
  u32 r0 = 0, r1 = 0;
  if ((u32)(t & ~63) < nc) {            // whole waves past nc skip the loop
    if (!dual) {
#pragma unroll 4
      for (u32 k = 0; k < nc; k += 2) { // 2 keys per ds_read_b128
        ulonglong2 pk = *(const ulonglong2*)&pool[k];
        r0 += (pk.x > my0) ? 1u : 0u;
        r0 += (pk.y > my0) ? 1u : 0u;
      }
    } else {
#pragma unroll 4
      for (u32 k = 0; k < nc; k += 2) {
        ulonglong2 pk = *(const ulonglong2*)&pool[k];
        r0 += (pk.x > my0) ? 1u : 0u;
        r0 += (pk.y > my0) ? 1u : 0u;
        r1 += (pk.x > my1) ? 1u : 0u;
        r1 += (pk.y > my1) ? 1u : 0u;
      }
    }
  }
  if (my0 != 0ULL && r0 < (u32)K_) spool[r0] = my0;
  if (dual && my1 != 0ULL && r1 < (u32)K_) spool[r1] = my1;
  __syncthreads();
  // spool[0..199] == exact top_k (desc score, ties by ascending index)

  // ---- decode boxes for top-200; idle threads 256+ zero rowmask ----
  float scv = 0.f;
  if (t < K_) {
    float x1 = 0.f, y1 = 0.f, x2 = 0.f, y2 = 0.f, area = 0.f;
    u64 e = spool[t];
    u32 kb = (u32)(e >> 32);
    if (kb != 0u) {
      scv = __uint_as_float(kb);
      u32 idx = 0xFFFFFFFFu - (u32)(e & 0xFFFFFFFFu);
      int nn = (idx < (u32)N_) ? (int)idx : (int)(idx - N_);
      float4 l = (idx < (u32)N_) ? loc1[(size_t)bimg * N_ + nn]
                                 : loc2[(size_t)bimg * N_ + nn];
      float4 d = dbox[nn];
      float cx = d.x + l.x * 0.1f * d.z;
      float cy = d.y + l.y * 0.1f * d.w;
      float w = d.z * __expf(l.z * 0.2f);
      float h = d.w * __expf(l.w * 0.2f);
      x1 = cx - w * 0.5f; y1 = cy - h * 0.5f;
      x2 = cx + w * 0.5f; y2 = cy + h * 0.5f;
      if (idx >= (u32)N_) {   // horizontal flip of second (TTA) view
        float tmp = 1.0f - x2; x2 = 1.0f - x1; x1 = tmp;
      }
      area = (x2 - x1) * (y2 - y1);
    }
    bb[t] = make_float4(x1, y1, x2, y2);
    bar[t] = area;
  } else if (t >= 256) {
    for (int i = t - 256; i < 4 * K_; i += 256) ((u64*)rowmask)[i] = 0ULL;
  }
  {
    bool myvalid = (t < K_) && (scv > CONF_T);
    u64 bal = __ballot(myvalid);
    if (lane == 0 && wv < 4) validmask[wv] = bal;
  }
  __syncthreads();

  // ---- triangle IoU: row j, cols j+1..199, split in half across 400 threads ----
  if (t < 2 * K_) {
    const int j = (t < K_) ? t : (t - K_);
    const int h = (t < K_) ? 0 : 1;
    const int L = K_ - 1 - j;             // #cols after j
    const int half = (L + 1) >> 1;
    const int s0c = j + 1 + (h ? half : 0);
    const int e0c = h ? K_ : (j + 1 + half);
    if (s0c < e0c) {
      float4 mb = bb[j];
      float ma = bar[j];
      for (int w = (s0c >> 6); w <= ((e0c - 1) >> 6); ++w) {
        int ka = (w << 6) > s0c ? (w << 6) : s0c;
        int kb2 = ((w + 1) << 6) < e0c ? ((w + 1) << 6) : e0c;
        u64 m = 0ULL;
        for (int k2 = ka; k2 < kb2; ++k2) {
          float4 obx = bb[k2];
          float ox1 = fmaxf(mb.x, obx.x);
          float oy1 = fmaxf(mb.y, obx.y);
          float ox2 = fminf(mb.z, obx.z);
          float oy2 = fminf(mb.w, obx.w);
          float inter = fmaxf(ox2 - ox1, 0.f) * fmaxf(oy2 - oy1, 0.f);
          float uni = ma + bar[k2] - inter;
          m |= (inter > NMS_T * uni) ? (1ULL << (k2 & 63)) : 0ULL;
        }
        if (m) atomicOr(&rowmask[j][w], m);
      }
    }
  }
  __syncthreads();
  // waves 1-7 are done; wave 0 finishes the block alone.

  // ---- static pipelined greedy scan, chunked by word (triangle: j>=64 never
  // touches word 0, etc.), then in-wave compact ----
  if (t < 64) {
    const u64 vv0 = validmask[0], vv1 = validmask[1];
    const u64 vv2 = validmask[2], vv3 = validmask[3];
    u64 s0 = 0, s1 = 0, s2 = 0, s3 = 0;
    u64 k0 = 0, k1 = 0, k2m = 0, k3 = 0;
#pragma unroll 8
    for (int j = 0; j < 64; ++j) {
      u64 q0 = rowmask[j][0], q1 = rowmask[j][1], q2 = rowmask[j][2], q3 = rowmask[j][3];
      u64 bit = 1ULL << j;
      if ((vv0 & bit) && !(s0 & bit)) { s0 |= q0; s1 |= q1; s2 |= q2; s3 |= q3; k0 |= bit; }
    }
#pragma unroll 8
    for (int j = 64; j < 128; ++j) {
      u64 q1 = rowmask[j][1], q2 = rowmask[j][2], q3 = rowmask[j][3];
      u64 bit = 1ULL << (j & 63);
      if ((vv1 & bit) && !(s1 & bit)) { s1 |= q1; s2 |= q2; s3 |= q3; k1 |= bit; }
    }
#pragma unroll 8
    for (int j = 128; j < 192; ++j) {
      u64 q2 = rowmask[j][2], q3 = rowmask[j][3];
      u64 bit = 1ULL << (j & 63);
      if ((vv2 & bit) && !(s2 & bit)) { s2 |= q2; s3 |= q3; k2m |= bit; }
    }
#pragma unroll
    for (int j = 192; j < K_; ++j) {
      u64 q3 = rowmask[j][3];
      u64 bit = 1ULL << (j & 63);
      if ((vv3 & bit) && !(s3 & bit)) { s3 |= q3; k3 |= bit; }
    }
    // ---- compact kept entries (lane-parallel within wave 0) ----
    const u32 n0 = (u32)__popcll(k0);
    const u32 n01 = n0 + (u32)__popcll(k1);
    const u32 n012 = n01 + (u32)__popcll(k2m);
    const u64 below = (1ULL << lane) - 1ULL;
#pragma unroll
    for (int w = 0; w < 4; ++w) {
      int j = (w << 6) + lane;
      if (j < K_) {
        u64 kw = (w == 0) ? k0 : (w == 1) ? k1 : (w == 2) ? k2m : k3;
        if ((kw >> lane) & 1ULL) {
          int pos2 = (int)__popcll(kw & below)
                  + (int)((w == 0) ? 0u : (w == 1) ? n0 : (w == 2) ? n01 : n012);
          u64 e = spool[j];
          float sc = __uint_as_float((u32)(e >> 32));
          float4 bx = bb[j];
          float* o = ob + (size_t)pos2 * 5;
          o[0] = sc; o[1] = bx.x; o[2] = bx.y; o[3] = bx.z; o[4] = bx.w;
        }
      }
    }
  }
}

extern "C" void kernel_launch(void* const* d_in, const int* in_sizes, int n_in,
                              void* d_out, int out_size, void* d_ws, size_t ws_size,
                              hipStream_t stream) {
  const float* loc1 = (const float*)d_in[0];
  const float* conf1 = (const float*)d_in[1];
  const float* loc2 = (const float*)d_in[2];
  const float* conf2 = (const float*)d_in[3];
  const float* dbox = (const float*)d_in[4];
  float* out = (float*)d_out;
  float* scores = (float*)d_ws;   // [B, NCLS, 2N] fp32 = 44.7 MB

  dim3 g1((N_ + TPB_S - 1) / TPB_S, B_, 2);
  softmax_kernel<<<g1, TPB_S, 0, stream>>>(conf1, conf2, scores);

  nms_kernel<<<B_ * NCLS, TPB_N, 0, stream>>>(
      scores, (const float4*)loc1, (const float4*)loc2, (const float4*)dbox, out);
}

// Round 9
// 145.335 us; speedup vs baseline: 1.3645x; 1.0429x over previous
//
#include <hip/hip_runtime.h>

#define B_ 32
#define N_ 8732
#define N2_ 17464
#define N4_ 4366      // N2_/4 exactly
#define C_ 21
#define NCLS 20
#define K_ 200
#define CONF_T 0.01f
#define NMS_T 0.45f
#define TPB_S 256
#define TPB_N 512
#define POOL 1024
#define RANKCAP 512   // refine-descent target (fallback path only)
#define HB0 2048      // level-0 bins (shift 15)
#define HB 1024       // refine-level bins (shift 5 then 0)
#define BIN0 30791u   // 0x3C23D70B >> 15: bin offset for level 0

typedef unsigned long long u64;
typedef unsigned int u32;

// ---------------------------------------------------------------------------
// Kernel 1 (round-6 hardware-verified, unchanged): softmax over C=21.
// Coalesced float4->LDS staging, per-row compute in registers, DIRECT global
// dword stores per class plane (lane-consecutive n -> coalesced 256B/wave).
// Grid: (ceil(N/256), B, 2 views).
// ---------------------------------------------------------------------------
__global__ __launch_bounds__(TPB_S) void softmax_kernel(
    const float* __restrict__ conf1, const float* __restrict__ conf2,
    float* __restrict__ scores)
{
  __shared__ float lds[TPB_S * C_];   // 21 KB
  const int t = threadIdx.x;
  const int tile = blockIdx.x * TPB_S;
  const int b = blockIdx.y;
  const int view = blockIdx.z;
  int cnt = N_ - tile; if (cnt > TPB_S) cnt = TPB_S;   // 256 or 28 (both %4==0)
  const float* conf = view ? conf2 : conf1;
  const float4* src = (const float4*)(conf + ((size_t)b * N_ + tile) * C_);  // 16B-aligned
  float4* l4 = (float4*)lds;
  const int n4 = (cnt * C_) >> 2;
  for (int i = t; i < n4; i += TPB_S) l4[i] = src[i];
  __syncthreads();
  if (t < cnt) {
    float x[C_];
#pragma unroll
    for (int i = 0; i < C_; ++i) x[i] = lds[t * C_ + i];  // stride-21: 2-way, free
    float m = x[0];
#pragma unroll
    for (int i = 1; i < C_; ++i) m = fmaxf(m, x[i]);
    float e[C_];
    float sum = 0.0f;
#pragma unroll
    for (int i = 0; i < C_; ++i) { e[i] = __expf(x[i] - m); sum += e[i]; }
    float inv = 1.0f / sum;   // one IEEE div, not 20
    float* o = scores + ((size_t)b * NCLS) * N2_ + (size_t)view * N_ + (tile + t);
#pragma unroll
    for (int c = 1; c < C_; ++c) { *o = e[c] * inv; o += N2_; }
  }
}

// ---------------------------------------------------------------------------
// Kernel 2: per-(image,class). Round-8 verified structure with the collect +
// rank phases replaced by BUCKETED rank-by-counting: after the in-place
// suffix sums (hist[h] = S[h] = #keys in bins >= h), collecting a candidate
// in bin h via pos = atomicSub(&hist[h],1)-1 bucket-sorts the pool by bin
// (bin h occupies [S[h+1], S[h])) AND leaves hist[h] = S[h+1] = the exact
// rank base for bin h. Rank = hist[h] + #{same-bin composites > mine}, bin
// populations ~tens -> replaces ballot-collect (288 instr/thr, wave-
// serialized) + all-pairs rank (625 instr/thr) with ~1 atomic/candidate and
// ~pop compares. Cross-bin order = key-high-bits order; within-bin uses the
// full composite compare; equal scores share a bin -> rank is bit-identical
// to the all-pairs loop. Fallback (cutoff bin > POOL, block-uniform): old
// refine + ballot-collect + all-pairs path. One 512-thread block per (b, c).
// ---------------------------------------------------------------------------
__global__ __launch_bounds__(TPB_N, 2) void nms_kernel(
    const float* __restrict__ scores,
    const float4* __restrict__ loc1,
    const float4* __restrict__ loc2,
    const float4* __restrict__ dbox,
    float* __restrict__ out)
{
  const int t = threadIdx.x;
  const int lane = t & 63;
  const int wv = t >> 6;
  const int bimg = blockIdx.x / NCLS;
  const int cls = 1 + (blockIdx.x % NCLS);
  const float4* sc4 = (const float4*)(scores + ((size_t)bimg * NCLS + (cls - 1)) * N2_);
  float* ob = out + ((size_t)bimg * C_ + cls) * K_ * 5;

  __shared__ u32 hist[HB0];              // 8 KB (L0: 2048 @shift15; refine: first 1024)
  __shared__ u64 pool[POOL] __attribute__((aligned(16)));  // 8 KB
  __shared__ u64 spool[256];             // 2 KB, rank-ordered top-200
  __shared__ float4 bb[K_];              // 3.2 KB
  __shared__ float bar[K_];
  __shared__ u64 rowmask[K_][4];         // 6.4 KB (triangle: row j has cols>j)
  __shared__ u64 validmask[4];
  __shared__ u32 wtot[8];
  __shared__ u32 sh_sel, sh_Sb, sh_Sn, sh_nc;

  // ---- fused output zeroing (replaces hipMemsetAsync) ----
  {
    const float4 z4 = make_float4(0.f, 0.f, 0.f, 0.f);
    if (t < 250) ((float4*)ob)[t] = z4;                      // own (b,cls) slice
    if (cls == 1 && t >= 256 && t < 506)                     // background class 0
      ((float4*)(out + (size_t)bimg * C_ * K_ * 5))[t - 256] = z4;
  }

  // ---- load this (b,c)'s 17464 scores into registers: the ONLY global pass ----
  float4 v[9];
#pragma unroll
  for (int k = 0; k < 9; ++k) {
    int i = t + k * TPB_N;
    v[k] = (i < N4_) ? sc4[i] : make_float4(0.f, 0.f, 0.f, 0.f);
  }

  // ---- zero L0 hist (2048) + pool (fallback b128 reads past nc need 0s) ----
  hist[t] = 0u; hist[t + 512] = 0u; hist[t + 1024] = 0u; hist[t + 1536] = 0u;
  pool[t] = 0ULL; pool[t + TPB_N] = 0ULL;
  if (t == 0) sh_nc = 0u;
  __syncthreads();

  // ---- level 0: 2048-bin histogram at shift 15 ----
  // valid keys 0x3C23D70B..0x3F800000 -> (key>>15)-30791 in [0,1721]
#pragma unroll
  for (int k = 0; k < 9; ++k) {
    float ss[4] = {v[k].x, v[k].y, v[k].z, v[k].w};
#pragma unroll
    for (int c2 = 0; c2 < 4; ++c2) {
      float s = ss[c2];
      if (s > CONF_T)
        atomicAdd(&hist[(__float_as_uint(s) >> 15) - BIN0], 1u);
    }
  }
  __syncthreads();

  // ---- suffix sums over 2048 bins (in place): hist[h] = S[h] ----
  {
    u32 c0 = hist[4 * t + 0], c1 = hist[4 * t + 1];
    u32 c2b = hist[4 * t + 2], c3 = hist[4 * t + 3];
    u32 T = c0 + c1 + c2b + c3;
    u32 x = T;
#pragma unroll
    for (int off = 1; off < 64; off <<= 1) {
      u32 y = __shfl_down(x, off);
      if (lane + off < 64) x += y;
    }                                   // x = suffix-incl sum of thread totals in wave
    if (lane == 0) wtot[wv] = x;
    __syncthreads();
    u32 wafter = 0;
    for (int w = wv + 1; w < 8; ++w) wafter += wtot[w];
    u32 after_me = (x - T) + wafter;    // totals of threads strictly after t
    u32 S3 = c3 + after_me, S2 = c2b + S3, S1 = c1 + S2, S0 = c0 + S1;
    hist[4 * t + 0] = S0; hist[4 * t + 1] = S1;
    hist[4 * t + 2] = S2; hist[4 * t + 3] = S3;
  }
  __syncthreads();

  // ---- select cutoff bin ----
  u32 loKey, selBin = 0, ncand, prefix = 0, Gacc = 0;
  bool fallback = false;
  {
    u32 total = hist[0];                // block-uniform
    if (total < (u32)K_) {
      loKey = 1u;                       // undershoot: take all valid (<200)
      ncand = total;
    } else {
      for (int h = t; h < HB0; h += TPB_N) {
        u32 Sb = hist[h];
        u32 Sn = (h + 1 < HB0) ? hist[h + 1] : 0u;
        if (Sb >= (u32)K_ && Sn < (u32)K_) { sh_sel = (u32)h; sh_Sb = Sb; sh_Sn = Sn; }
      }
      __syncthreads();                  // uniform branch: total is block-uniform
      selBin = sh_sel;
      prefix = sh_sel + BIN0;           // real key>>15 value
      loKey = prefix << 15;
      ncand = sh_Sb;
      Gacc = sh_Sn;
      fallback = sh_Sb > (u32)POOL;     // pathological: one bin holding >1024
    }
  }

  if (t < 256) spool[t] = 0ULL;         // rank writes come after a barrier

  if (!fallback) {
    // ---- bucketed collect: pos = --hist[bin]; bin h fills [S[h+1],S[h]) ----
#pragma unroll
    for (int k = 0; k < 9; ++k) {
      int i = t + k * TPB_N;
      float ss[4] = {v[k].x, v[k].y, v[k].z, v[k].w};
#pragma unroll
      for (int c2 = 0; c2 < 4; ++c2) {
        float s = ss[c2];
        u32 key = __float_as_uint(s);
        if (s > CONF_T && key >= loKey) {
          u32 h = (key >> 15) - BIN0;
          u32 pos = atomicSub(&hist[h], 1u) - 1u;
          pool[pos] = ((u64)key << 32) | (u64)(0xFFFFFFFFu - (u32)(i * 4 + c2));
        }
      }
    }
    __syncthreads();
    // post-collect: hist[h] == S[h+1] for every bin >= selBin (rank base).
    // ---- bin-local rank: base + #{same-bin composites > mine} ----
    for (int slot = t; slot < (int)ncand; slot += TPB_N) {
      u64 e = pool[slot];
      u32 h = ((u32)(e >> 32) >> 15) - BIN0;
      u32 base = hist[h];
      u32 up = (h == selBin) ? ncand : hist[h - 1];   // bin range end
      u32 r = base;
      for (u32 q = base; q < up; ++q) r += (pool[q] > e) ? 1u : 0u;
      if (r < (u32)K_) spool[r] = e;
    }
  } else {
    // ---- FALLBACK (rare, block-uniform): refine + ballot + all-pairs ----
    bool needMore = true;
    for (int lvl = 1; lvl <= 2 && needMore; ++lvl) {
      const int shift = (lvl == 1) ? 5 : 0;
      const int mshift = (lvl == 1) ? 15 : 5;
      const u32 bmask = (lvl == 1) ? 1023u : 31u;
      for (int h = t; h < HB; h += TPB_N) hist[h] = 0u;
      __syncthreads();
#pragma unroll
      for (int k = 0; k < 9; ++k) {
        float ss[4] = {v[k].x, v[k].y, v[k].z, v[k].w};
#pragma unroll
        for (int c2 = 0; c2 < 4; ++c2) {
          float s = ss[c2];
          if (s > CONF_T) {
            u32 key = __float_as_uint(s);
            if ((key >> mshift) == prefix)
              atomicAdd(&hist[(key >> shift) & bmask], 1u);
          }
        }
      }
      __syncthreads();
      u32 c0 = hist[2 * t], c1 = hist[2 * t + 1];
      u32 T = c0 + c1;
      u32 x = T;
#pragma unroll
      for (int off = 1; off < 64; off <<= 1) {
        u32 y = __shfl_down(x, off);
        if (lane + off < 64) x += y;
      }
      if (lane == 0) wtot[wv] = x;
      __syncthreads();
      u32 wafter = 0;
      for (int w = wv + 1; w < 8; ++w) wafter += wtot[w];
      u32 after_me = (x - T) + wafter;
      u32 S1 = c1 + after_me, S0 = c0 + S1;
      hist[2 * t] = S0; hist[2 * t + 1] = S1;
      __syncthreads();
      u32 need = (u32)K_ - Gacc;
      for (int h = t; h < HB; h += TPB_N) {
        u32 Sb = hist[h];
        u32 Sn2 = (h + 1 < HB) ? hist[h + 1] : 0u;
        if (Sb >= need && Sn2 < need) { sh_sel = (u32)h; sh_Sb = Sb; sh_Sn = Sn2; }
      }
      __syncthreads();
      prefix = (prefix << ((lvl == 1) ? 10 : 5)) | sh_sel;
      u32 candTotal = Gacc + sh_Sb;
      Gacc += sh_Sn;
      loKey = prefix << shift;
      needMore = (candTotal > (u32)RANKCAP) && (lvl < 2);
    }
    // ---- ballot-collect candidates into pool, 1 atomic/wave ----
#pragma unroll
    for (int k = 0; k < 9; ++k) {
      int i = t + k * TPB_N;
      float ss[4] = {v[k].x, v[k].y, v[k].z, v[k].w};
#pragma unroll
      for (int c2 = 0; c2 < 4; ++c2) {
        float s = ss[c2];
        u32 key = __float_as_uint(s);
        bool pred = (s > CONF_T) && (key >= loKey);
        u64 bal = __ballot(pred);
        if (bal) {
          u32 wb = 0;
          if (lane == 0) wb = atomicAdd(&sh_nc, (u32)__popcll(bal));
          wb = __shfl(wb, 0);
          if (pred) {
            u32 pos = wb + (u32)__popcll(bal & ((1ULL << lane) - 1ULL));
            if (pos < (u32)POOL)
              pool[pos] = ((u64)key << 32) | (u64)(0xFFFFFFFFu - (u32)(i * 4 + c2));
          }
        }
      }
    }
    __syncthreads();
    // ---- all-pairs rank (pool pre-zeroed; b128 reads past nc see 0) ----
    u32 nc = sh_nc < (u32)POOL ? sh_nc : (u32)POOL;
    const bool dual = nc > (u32)TPB_N;
    u64 my0 = (t < (int)nc) ? pool[t] : 0ULL;
    u64 my1 = (dual && t + TPB_N < (int)nc) ? pool[t + TPB_N] : 0ULL;
    u32 r0 = 0, r1 = 0;
    if ((u32)(t & ~63) < nc) {
      if (!dual) {
#pragma unroll 4
        for (u32 k = 0; k < nc; k += 2) {
          ulonglong2 pk = *(const ulonglong2*)&pool[k];
          r0 += (pk.x > my0) ? 1u : 0u;
          r0 += (pk.y > my0) ? 1u : 0u;
        }
      } else {
#pragma unroll 4
        for (u32 k = 0; k < nc; k += 2) {
          ulonglong2 pk = *(const ulonglong2*)&pool[k];
          r0 += (pk.x > my0) ? 1u : 0u;
          r0 += (pk.y > my0) ? 1u : 0u;
          r1 += (pk.x > my1) ? 1u : 0u;
          r1 += (pk.y > my1) ? 1u : 0u;
        }
      }
    }
    if (my0 != 0ULL && r0 < (u32)K_) spool[r0] = my0;
    if (dual && my1 != 0ULL && r1 < (u32)K_) spool[r1] = my1;
  }
  __syncthreads();
  // spool[0..199] == exact top_k (desc score, ties by ascending index)

  // ---- decode boxes for top-200; idle threads 256+ zero rowmask ----
  float scv = 0.f;
  if (t < K_) {
    float x1 = 0.f, y1 = 0.f, x2 = 0.f, y2 = 0.f, area = 0.f;
    u64 e = spool[t];
    u32 kb = (u32)(e >> 32);
    if (kb != 0u) {
      scv = __uint_as_float(kb);
      u32 idx = 0xFFFFFFFFu - (u32)(e & 0xFFFFFFFFu);
      int nn = (idx < (u32)N_) ? (int)idx : (int)(idx - N_);
      float4 l = (idx < (u32)N_) ? loc1[(size_t)bimg * N_ + nn]
                                 : loc2[(size_t)bimg * N_ + nn];
      float4 d = dbox[nn];
      float cx = d.x + l.x * 0.1f * d.z;
      float cy = d.y + l.y * 0.1f * d.w;
      float w = d.z * __expf(l.z * 0.2f);
      float h = d.w * __expf(l.w * 0.2f);
      x1 = cx - w * 0.5f; y1 = cy - h * 0.5f;
      x2 = cx + w * 0.5f; y2 = cy + h * 0.5f;
      if (idx >= (u32)N_) {   // horizontal flip of second (TTA) view
        float tmp = 1.0f - x2; x2 = 1.0f - x1; x1 = tmp;
      }
      area = (x2 - x1) * (y2 - y1);
    }
    bb[t] = make_float4(x1, y1, x2, y2);
    bar[t] = area;
  } else if (t >= 256) {
    for (int i = t - 256; i < 4 * K_; i += 256) ((u64*)rowmask)[i] = 0ULL;
  }
  {
    bool myvalid = (t < K_) && (scv > CONF_T);
    u64 bal = __ballot(myvalid);
    if (lane == 0 && wv < 4) validmask[wv] = bal;
  }
  __syncthreads();

  // ---- triangle IoU: row j, cols j+1..199, split in half across 400 threads ----
  if (t < 2 * K_) {
    const int j = (t < K_) ? t : (t - K_);
    const int h = (t < K_) ? 0 : 1;
    const int L = K_ - 1 - j;             // #cols after j
    const int half = (L + 1) >> 1;
    const int s0c = j + 1 + (h ? half : 0);
    const int e0c = h ? K_ : (j + 1 + half);
    if (s0c < e0c) {
      float4 mb = bb[j];
      float ma = bar[j];
      for (int w = (s0c >> 6); w <= ((e0c - 1) >> 6); ++w) {
        int ka = (w << 6) > s0c ? (w << 6) : s0c;
        int kb2 = ((w + 1) << 6) < e0c ? ((w + 1) << 6) : e0c;
        u64 m = 0ULL;
        for (int k2 = ka; k2 < kb2; ++k2) {
          float4 obx = bb[k2];
          float ox1 = fmaxf(mb.x, obx.x);
          float oy1 = fmaxf(mb.y, obx.y);
          float ox2 = fminf(mb.z, obx.z);
          float oy2 = fminf(mb.w, obx.w);
          float inter = fmaxf(ox2 - ox1, 0.f) * fmaxf(oy2 - oy1, 0.f);
          float uni = ma + bar[k2] - inter;
          m |= (inter > NMS_T * uni) ? (1ULL << (k2 & 63)) : 0ULL;
        }
        if (m) atomicOr(&rowmask[j][w], m);
      }
    }
  }
  __syncthreads();
  // waves 1-7 are done; wave 0 finishes the block alone.

  // ---- static pipelined greedy scan, chunked by word (triangle: j>=64 never
  // touches word 0, etc.), then in-wave compact ----
  if (t < 64) {
    const u64 vv0 = validmask[0], vv1 = validmask[1];
    const u64 vv2 = validmask[2], vv3 = validmask[3];
    u64 s0 = 0, s1 = 0, s2 = 0, s3 = 0;
    u64 k0 = 0, k1 = 0, k2m = 0, k3 = 0;
#pragma unroll 8
    for (int j = 0; j < 64; ++j) {
      u64 q0 = rowmask[j][0], q1 = rowmask[j][1], q2 = rowmask[j][2], q3 = rowmask[j][3];
      u64 bit = 1ULL << j;
      if ((vv0 & bit) && !(s0 & bit)) { s0 |= q0; s1 |= q1; s2 |= q2; s3 |= q3; k0 |= bit; }
    }
#pragma unroll 8
    for (int j = 64; j < 128; ++j) {
      u64 q1 = rowmask[j][1], q2 = rowmask[j][2], q3 = rowmask[j][3];
      u64 bit = 1ULL << (j & 63);
      if ((vv1 & bit) && !(s1 & bit)) { s1 |= q1; s2 |= q2; s3 |= q3; k1 |= bit; }
    }
#pragma unroll 8
    for (int j = 128; j < 192; ++j) {
      u64 q2 = rowmask[j][2], q3 = rowmask[j][3];
      u64 bit = 1ULL << (j & 63);
      if ((vv2 & bit) && !(s2 & bit)) { s2 |= q2; s3 |= q3; k2m |= bit; }
    }
#pragma unroll
    for (int j = 192; j < K_; ++j) {
      u64 q3 = rowmask[j][3];
      u64 bit = 1ULL << (j & 63);
      if ((vv3 & bit) && !(s3 & bit)) { s3 |= q3; k3 |= bit; }
    }
    // ---- compact kept entries (lane-parallel within wave 0) ----
    const u32 n0 = (u32)__popcll(k0);
    const u32 n01 = n0 + (u32)__popcll(k1);
    const u32 n012 = n01 + (u32)__popcll(k2m);
    const u64 below = (1ULL << lane) - 1ULL;
#pragma unroll
    for (int w = 0; w < 4; ++w) {
      int j = (w << 6) + lane;
      if (j < K_) {
        u64 kw = (w == 0) ? k0 : (w == 1) ? k1 : (w == 2) ? k2m : k3;
        if ((kw >> lane) & 1ULL) {
          int pos2 = (int)__popcll(kw & below)
                  + (int)((w == 0) ? 0u : (w == 1) ? n0 : (w == 2) ? n01 : n012);
          u64 e = spool[j];
          float sc = __uint_as_float((u32)(e >> 32));
          float4 bx = bb[j];
          float* o = ob + (size_t)pos2 * 5;
          o[0] = sc; o[1] = bx.x; o[2] = bx.y; o[3] = bx.z; o[4] = bx.w;
        }
      }
    }
  }
}

extern "C" void kernel_launch(void* const* d_in, const int* in_sizes, int n_in,
                              void* d_out, int out_size, void* d_ws, size_t ws_size,
                              hipStream_t stream) {
  const float* loc1 = (const float*)d_in[0];
  const float* conf1 = (const float*)d_in[1];
  const float* loc2 = (const float*)d_in[2];
  const float* conf2 = (const float*)d_in[3];
  const float* dbox = (const float*)d_in[4];
  float* out = (float*)d_out;
  float* scores = (float*)d_ws;   // [B, NCLS, 2N] fp32 = 44.7 MB

  dim3 g1((N_ + TPB_S - 1) / TPB_S, B_, 2);
  softmax_kernel<<<g1, TPB_S, 0, stream>>>(conf1, conf2, scores);

  nms_kernel<<<B_ * NCLS, TPB_N, 0, stream>>>(
      scores, (const float4*)loc1, (const float4*)loc2, (const float4*)dbox, out);
}